// Round 1
// baseline (1483.976 us; speedup 1.0000x reference)
//
#include <hip/hip_runtime.h>

#define NROWS 16   // rows per block iteration in the GEMM kernels

// out[r][c] = sum_k feat[r][k] * W[c][k]   (i.e. feat @ W.T)
// W staged transposed in LDS with +1 padding (conflict-free), feat rows
// staged in LDS and broadcast. Each thread: 4 rows x 2 cols accumulators.
__global__ __launch_bounds__(256) void gemm_h_kernel(
    const float* __restrict__ feat,
    const float* __restrict__ W,
    float* __restrict__ h, int n) {
  __shared__ float wT[128][129];
  __shared__ float fr[NROWS][128];
  const int tid = threadIdx.x;
  for (int i = tid; i < 128 * 128; i += 256) {
    int c = i >> 7, k = i & 127;
    wT[k][c] = W[i];
  }
  const int wv = tid >> 6;
  const int lane = tid & 63;
  const int r0 = wv * 4;
  const int ngrp = (n + NROWS - 1) / NROWS;
  for (int rg = blockIdx.x; rg < ngrp; rg += gridDim.x) {
    const int row0 = rg * NROWS;
    __syncthreads();  // waits for W load (first iter) / prior compute (later)
    if (row0 + NROWS <= n) {
      const float4* fsrc = (const float4*)(feat + (size_t)row0 * 128);
      float4* fdst = (float4*)&fr[0][0];
      fdst[tid] = fsrc[tid];
      fdst[tid + 256] = fsrc[tid + 256];
    } else {
      for (int i = tid; i < NROWS * 128; i += 256) {
        int r = i >> 7;
        fr[r][i & 127] = (row0 + r < n) ? feat[(size_t)(row0 + r) * 128 + (i & 127)] : 0.f;
      }
    }
    __syncthreads();
    float a00 = 0, a01 = 0, a10 = 0, a11 = 0, a20 = 0, a21 = 0, a30 = 0, a31 = 0;
#pragma unroll 4
    for (int k = 0; k < 128; ++k) {
      float w0 = wT[k][lane];
      float w1 = wT[k][lane + 64];
      float f0 = fr[r0 + 0][k];
      float f1 = fr[r0 + 1][k];
      float f2 = fr[r0 + 2][k];
      float f3 = fr[r0 + 3][k];
      a00 += f0 * w0; a01 += f0 * w1;
      a10 += f1 * w0; a11 += f1 * w1;
      a20 += f2 * w0; a21 += f2 * w1;
      a30 += f3 * w0; a31 += f3 * w1;
    }
    const int rr = row0 + r0;
    if (rr + 0 < n) { h[(size_t)(rr + 0) * 128 + lane] = a00; h[(size_t)(rr + 0) * 128 + lane + 64] = a01; }
    if (rr + 1 < n) { h[(size_t)(rr + 1) * 128 + lane] = a10; h[(size_t)(rr + 1) * 128 + lane + 64] = a11; }
    if (rr + 2 < n) { h[(size_t)(rr + 2) * 128 + lane] = a20; h[(size_t)(rr + 2) * 128 + lane + 64] = a21; }
    if (rr + 3 < n) { h[(size_t)(rr + 3) * 128 + lane] = a30; h[(size_t)(rr + 3) * 128 + lane + 64] = a31; }
  }
}

// Per edge: acc[dst] += h[src] * w  (f32 atomics), deg[dst] += 1.
// 32 threads per edge, float4 per thread.
__global__ __launch_bounds__(256) void scatter_kernel(
    const float* __restrict__ h, const int* __restrict__ src,
    const int* __restrict__ dst, const float* __restrict__ ew,
    float* __restrict__ acc, int* __restrict__ deg, int E) {
  int t = blockIdx.x * 256 + threadIdx.x;
  int e = t >> 5;
  if (e >= E) return;
  int q = t & 31;
  int s = src[e];
  int d = dst[e];
  float w = ew[e];
  const float4 hv = *(const float4*)(h + (size_t)s * 128 + q * 4);
  float* a = acc + (size_t)d * 128 + q * 4;
  atomicAdd(a + 0, hv.x * w);
  atomicAdd(a + 1, hv.y * w);
  atomicAdd(a + 2, hv.z * w);
  atomicAdd(a + 3, hv.w * w);
  if (q == 0) atomicAdd(deg + d, 1);
}

// out[r][c] = feat[r]·Ws[c] + b[c] + acc[r][c] / max(deg[r],1)
// acc IS d_out (read then overwritten by the same thread).
__global__ __launch_bounds__(256) void finalize_kernel(
    const float* __restrict__ feat,
    const float* __restrict__ W,
    const float* __restrict__ b,
    float* __restrict__ out,
    const int* __restrict__ deg, int n) {
  __shared__ float wT[128][129];
  __shared__ float fr[NROWS][128];
  const int tid = threadIdx.x;
  for (int i = tid; i < 128 * 128; i += 256) {
    int c = i >> 7, k = i & 127;
    wT[k][c] = W[i];
  }
  const int wv = tid >> 6;
  const int lane = tid & 63;
  const int r0 = wv * 4;
  const float b0 = b[lane];
  const float b1 = b[lane + 64];
  const int ngrp = (n + NROWS - 1) / NROWS;
  for (int rg = blockIdx.x; rg < ngrp; rg += gridDim.x) {
    const int row0 = rg * NROWS;
    __syncthreads();
    if (row0 + NROWS <= n) {
      const float4* fsrc = (const float4*)(feat + (size_t)row0 * 128);
      float4* fdst = (float4*)&fr[0][0];
      fdst[tid] = fsrc[tid];
      fdst[tid + 256] = fsrc[tid + 256];
    } else {
      for (int i = tid; i < NROWS * 128; i += 256) {
        int r = i >> 7;
        fr[r][i & 127] = (row0 + r < n) ? feat[(size_t)(row0 + r) * 128 + (i & 127)] : 0.f;
      }
    }
    __syncthreads();
    float a00 = 0, a01 = 0, a10 = 0, a11 = 0, a20 = 0, a21 = 0, a30 = 0, a31 = 0;
#pragma unroll 4
    for (int k = 0; k < 128; ++k) {
      float w0 = wT[k][lane];
      float w1 = wT[k][lane + 64];
      float f0 = fr[r0 + 0][k];
      float f1 = fr[r0 + 1][k];
      float f2 = fr[r0 + 2][k];
      float f3 = fr[r0 + 3][k];
      a00 += f0 * w0; a01 += f0 * w1;
      a10 += f1 * w0; a11 += f1 * w1;
      a20 += f2 * w0; a21 += f2 * w1;
      a30 += f3 * w0; a31 += f3 * w1;
    }
    const int rr = row0 + r0;
    if (rr + 0 < n) {
      float dg = fmaxf((float)deg[rr + 0], 1.0f);
      size_t idx = (size_t)(rr + 0) * 128 + lane;
      float s0 = out[idx], s1 = out[idx + 64];
      out[idx] = a00 + b0 + s0 / dg;
      out[idx + 64] = a01 + b1 + s1 / dg;
    }
    if (rr + 1 < n) {
      float dg = fmaxf((float)deg[rr + 1], 1.0f);
      size_t idx = (size_t)(rr + 1) * 128 + lane;
      float s0 = out[idx], s1 = out[idx + 64];
      out[idx] = a10 + b0 + s0 / dg;
      out[idx + 64] = a11 + b1 + s1 / dg;
    }
    if (rr + 2 < n) {
      float dg = fmaxf((float)deg[rr + 2], 1.0f);
      size_t idx = (size_t)(rr + 2) * 128 + lane;
      float s0 = out[idx], s1 = out[idx + 64];
      out[idx] = a20 + b0 + s0 / dg;
      out[idx + 64] = a21 + b1 + s1 / dg;
    }
    if (rr + 3 < n) {
      float dg = fmaxf((float)deg[rr + 3], 1.0f);
      size_t idx = (size_t)(rr + 3) * 128 + lane;
      float s0 = out[idx], s1 = out[idx + 64];
      out[idx] = a30 + b0 + s0 / dg;
      out[idx + 64] = a31 + b1 + s1 / dg;
    }
  }
}

extern "C" void kernel_launch(void* const* d_in, const int* in_sizes, int n_in,
                              void* d_out, int out_size, void* d_ws, size_t ws_size,
                              hipStream_t stream) {
  const float* feat = (const float*)d_in[0];
  const int* src = (const int*)d_in[1];
  const int* dst = (const int*)d_in[2];
  const float* ew = (const float*)d_in[3];
  const float* Wn = (const float*)d_in[4];
  const float* Ws = (const float*)d_in[5];
  const float* bs = (const float*)d_in[6];
  const int n = in_sizes[0] / 128;
  const int E = in_sizes[1];
  float* out = (float*)d_out;

  float* h = (float*)d_ws;                                      // n*128 f32 = 25.6 MB
  int* deg = (int*)((char*)d_ws + (size_t)n * 128 * sizeof(float));  // n int32

  hipMemsetAsync(d_out, 0, (size_t)out_size * sizeof(float), stream);
  hipMemsetAsync(deg, 0, (size_t)n * sizeof(int), stream);

  const int ngrp = (n + NROWS - 1) / NROWS;
  const int gblocks = ngrp < 512 ? ngrp : 512;
  gemm_h_kernel<<<gblocks, 256, 0, stream>>>(feat, Wn, h, n);

  const long long sthreads = (long long)E * 32;
  const int sblocks = (int)((sthreads + 255) / 256);
  scatter_kernel<<<sblocks, 256, 0, stream>>>(h, src, dst, ew, out, deg, E);

  finalize_kernel<<<gblocks, 256, 0, stream>>>(feat, Ws, bs, out, deg, n);
}

// Round 3
// 280.290 us; speedup vs baseline: 5.2944x; 5.2944x over previous
//
#include <hip/hip_runtime.h>

#define NROWS 16

// ---------------- CSR build ----------------

__global__ __launch_bounds__(256) void deg_kernel(
    const int* __restrict__ dst, int* __restrict__ rowptr, int E) {
  int e = blockIdx.x * 256 + threadIdx.x;
  if (e < E) atomicAdd(&rowptr[dst[e] + 1], 1);
}

// scan1: per-block inclusive scan of 1024 elements (4/thread), in place.
__global__ __launch_bounds__(256) void scan1_kernel(
    int* __restrict__ data, int* __restrict__ bsum, int total) {
  __shared__ int tsum[256];
  const int tid = threadIdx.x;
  const int base = blockIdx.x * 1024 + tid * 4;
  int v0 = 0, v1 = 0, v2 = 0, v3 = 0;
  if (base + 3 < total) {
    int4 v = *(const int4*)(data + base);
    v0 = v.x; v1 = v.y; v2 = v.z; v3 = v.w;
  } else {
    if (base + 0 < total) v0 = data[base + 0];
    if (base + 1 < total) v1 = data[base + 1];
    if (base + 2 < total) v2 = data[base + 2];
    if (base + 3 < total) v3 = data[base + 3];
  }
  v1 += v0; v2 += v1; v3 += v2;           // inclusive within thread
  tsum[tid] = v3;
  __syncthreads();
  for (int off = 1; off < 256; off <<= 1) {
    int t = (tid >= off) ? tsum[tid - off] : 0;
    __syncthreads();
    tsum[tid] += t;
    __syncthreads();
  }
  const int excl = (tid > 0) ? tsum[tid - 1] : 0;
  v0 += excl; v1 += excl; v2 += excl; v3 += excl;
  if (base + 3 < total) {
    *(int4*)(data + base) = make_int4(v0, v1, v2, v3);
  } else {
    if (base + 0 < total) data[base + 0] = v0;
    if (base + 1 < total) data[base + 1] = v1;
    if (base + 2 < total) data[base + 2] = v2;
    if (base + 3 < total) data[base + 3] = v3;
  }
  if (tid == 255) bsum[blockIdx.x] = tsum[255];
}

// scan2: exclusive scan of nb (<=64) block sums, single wave.
__global__ __launch_bounds__(64) void scan2_kernel(
    const int* __restrict__ bsum, int* __restrict__ bsumEx, int nb) {
  const int lane = threadIdx.x;
  int v = (lane < nb) ? bsum[lane] : 0;
  const int own = v;
  for (int off = 1; off < 64; off <<= 1) {
    int u = __shfl_up(v, off);
    if (lane >= off) v += u;
  }
  if (lane < nb) bsumEx[lane] = v - own;
}

// scan3: add block offset; also emit cursor[i] = rowptr[i] for i < n.
__global__ __launch_bounds__(256) void scan3_kernel(
    int* __restrict__ data, int* __restrict__ cursor,
    const int* __restrict__ bsumEx, int total, int n) {
  const int add = bsumEx[blockIdx.x];
  const int base = blockIdx.x * 1024 + threadIdx.x * 4;
#pragma unroll
  for (int k = 0; k < 4; ++k) {
    int i = base + k;
    if (i < total) {
      int val = data[i] + add;
      data[i] = val;
      if (i < n) cursor[i] = val;
    }
  }
}

__global__ __launch_bounds__(256) void fill_kernel(
    const int* __restrict__ src, const int* __restrict__ dst,
    const float* __restrict__ ew, int* __restrict__ cursor,
    int* __restrict__ col, float* __restrict__ wgt, int E) {
  int e = blockIdx.x * 256 + threadIdx.x;
  if (e >= E) return;
  int d = dst[e];
  int pos = atomicAdd(&cursor[d], 1);
  col[pos] = src[e];
  wgt[pos] = ew[e];
}

// ---------------- gather: agg[d] = (sum_e feat[src_e]*w_e) / max(deg,1) ----------------
// One wave per dst node; lane handles channels {lane, lane+64}.
__global__ __launch_bounds__(256) void gather_kernel(
    const float* __restrict__ feat, const int* __restrict__ rowptr,
    const int* __restrict__ col, const float* __restrict__ wgt,
    float* __restrict__ agg, int n) {
  const int wid = (blockIdx.x * 256 + threadIdx.x) >> 6;
  const int lane = threadIdx.x & 63;
  if (wid >= n) return;
  const int s = rowptr[wid];
  const int e = rowptr[wid + 1];
  float acc0 = 0.f, acc1 = 0.f;
  for (int j = s; j < e; ++j) {
    const int c = col[j];
    const float w = wgt[j];
    const float* fp = feat + (size_t)c * 128;
    acc0 += fp[lane] * w;
    acc1 += fp[lane + 64] * w;
  }
  const float sc = 1.0f / fmaxf((float)(e - s), 1.0f);
  agg[(size_t)wid * 128 + lane] = acc0 * sc;
  agg[(size_t)wid * 128 + lane + 64] = acc1 * sc;
}

// ---------------- GEMM: out = in @ W.T ----------------
__global__ __launch_bounds__(256) void gemm_h_kernel(
    const float* __restrict__ feat,
    const float* __restrict__ W,
    float* __restrict__ h, int n) {
  __shared__ float wT[128][129];
  __shared__ float fr[NROWS][128];
  const int tid = threadIdx.x;
  for (int i = tid; i < 128 * 128; i += 256) {
    int c = i >> 7, k = i & 127;
    wT[k][c] = W[i];
  }
  const int wv = tid >> 6;
  const int lane = tid & 63;
  const int r0 = wv * 4;
  const int ngrp = (n + NROWS - 1) / NROWS;
  for (int rg = blockIdx.x; rg < ngrp; rg += gridDim.x) {
    const int row0 = rg * NROWS;
    __syncthreads();
    if (row0 + NROWS <= n) {
      const float4* fsrc = (const float4*)(feat + (size_t)row0 * 128);
      float4* fdst = (float4*)&fr[0][0];
      fdst[tid] = fsrc[tid];
      fdst[tid + 256] = fsrc[tid + 256];
    } else {
      for (int i = tid; i < NROWS * 128; i += 256) {
        int r = i >> 7;
        fr[r][i & 127] = (row0 + r < n) ? feat[(size_t)(row0 + r) * 128 + (i & 127)] : 0.f;
      }
    }
    __syncthreads();
    float a00 = 0, a01 = 0, a10 = 0, a11 = 0, a20 = 0, a21 = 0, a30 = 0, a31 = 0;
#pragma unroll 4
    for (int k = 0; k < 128; ++k) {
      float w0 = wT[k][lane];
      float w1 = wT[k][lane + 64];
      float f0 = fr[r0 + 0][k];
      float f1 = fr[r0 + 1][k];
      float f2 = fr[r0 + 2][k];
      float f3 = fr[r0 + 3][k];
      a00 += f0 * w0; a01 += f0 * w1;
      a10 += f1 * w0; a11 += f1 * w1;
      a20 += f2 * w0; a21 += f2 * w1;
      a30 += f3 * w0; a31 += f3 * w1;
    }
    const int rr = row0 + r0;
    if (rr + 0 < n) { h[(size_t)(rr + 0) * 128 + lane] = a00; h[(size_t)(rr + 0) * 128 + lane + 64] = a01; }
    if (rr + 1 < n) { h[(size_t)(rr + 1) * 128 + lane] = a10; h[(size_t)(rr + 1) * 128 + lane + 64] = a11; }
    if (rr + 2 < n) { h[(size_t)(rr + 2) * 128 + lane] = a20; h[(size_t)(rr + 2) * 128 + lane + 64] = a21; }
    if (rr + 3 < n) { h[(size_t)(rr + 3) * 128 + lane] = a30; h[(size_t)(rr + 3) * 128 + lane + 64] = a31; }
  }
}

// out = feat @ Ws.T + b + neigh   (neigh read from ws)
__global__ __launch_bounds__(256) void finalize_kernel(
    const float* __restrict__ feat,
    const float* __restrict__ W,
    const float* __restrict__ b,
    const float* __restrict__ neigh,
    float* __restrict__ out, int n) {
  __shared__ float wT[128][129];
  __shared__ float fr[NROWS][128];
  const int tid = threadIdx.x;
  for (int i = tid; i < 128 * 128; i += 256) {
    int c = i >> 7, k = i & 127;
    wT[k][c] = W[i];
  }
  const int wv = tid >> 6;
  const int lane = tid & 63;
  const int r0 = wv * 4;
  const float b0 = b[lane];
  const float b1 = b[lane + 64];
  const int ngrp = (n + NROWS - 1) / NROWS;
  for (int rg = blockIdx.x; rg < ngrp; rg += gridDim.x) {
    const int row0 = rg * NROWS;
    __syncthreads();
    if (row0 + NROWS <= n) {
      const float4* fsrc = (const float4*)(feat + (size_t)row0 * 128);
      float4* fdst = (float4*)&fr[0][0];
      fdst[tid] = fsrc[tid];
      fdst[tid + 256] = fsrc[tid + 256];
    } else {
      for (int i = tid; i < NROWS * 128; i += 256) {
        int r = i >> 7;
        fr[r][i & 127] = (row0 + r < n) ? feat[(size_t)(row0 + r) * 128 + (i & 127)] : 0.f;
      }
    }
    __syncthreads();
    float a00 = 0, a01 = 0, a10 = 0, a11 = 0, a20 = 0, a21 = 0, a30 = 0, a31 = 0;
#pragma unroll 4
    for (int k = 0; k < 128; ++k) {
      float w0 = wT[k][lane];
      float w1 = wT[k][lane + 64];
      float f0 = fr[r0 + 0][k];
      float f1 = fr[r0 + 1][k];
      float f2 = fr[r0 + 2][k];
      float f3 = fr[r0 + 3][k];
      a00 += f0 * w0; a01 += f0 * w1;
      a10 += f1 * w0; a11 += f1 * w1;
      a20 += f2 * w0; a21 += f2 * w1;
      a30 += f3 * w0; a31 += f3 * w1;
    }
    const int rr = row0 + r0;
#pragma unroll
    for (int r = 0; r < 4; ++r) {
      if (rr + r < n) {
        size_t idx = (size_t)(rr + r) * 128 + lane;
        float aa0 = (r == 0) ? a00 : (r == 1) ? a10 : (r == 2) ? a20 : a30;
        float aa1 = (r == 0) ? a01 : (r == 1) ? a11 : (r == 2) ? a21 : a31;
        out[idx] = aa0 + b0 + neigh[idx];
        out[idx + 64] = aa1 + b1 + neigh[idx + 64];
      }
    }
  }
}

extern "C" void kernel_launch(void* const* d_in, const int* in_sizes, int n_in,
                              void* d_out, int out_size, void* d_ws, size_t ws_size,
                              hipStream_t stream) {
  const float* feat = (const float*)d_in[0];
  const int* src = (const int*)d_in[1];
  const int* dst = (const int*)d_in[2];
  const float* ew = (const float*)d_in[3];
  const float* Wn = (const float*)d_in[4];
  const float* Ws = (const float*)d_in[5];
  const float* bs = (const float*)d_in[6];
  const int n = in_sizes[0] / 128;
  const int E = in_sizes[1];
  float* out = (float*)d_out;

  // ws layout (byte offsets, aligned). CSR scratch lives in the low ~7 MB;
  // neigh (written by gemm1 AFTER gather has consumed the CSR) overlaps it
  // from offset 0. footprint = max(CSR ~7MB, neigh 25.6MB) = 25.6MB.
  char* w = (char*)d_ws;
  size_t off_col = 0;                                         // E ints
  size_t off_wgt = off_col + (size_t)E * 4;                   // E floats
  size_t off_rowptr = off_wgt + (size_t)E * 4;                // n+1 ints
  size_t off_cursor = (off_rowptr + (size_t)(n + 1) * 4 + 255) & ~(size_t)255;  // n ints
  size_t off_bsum = (off_cursor + (size_t)n * 4 + 255) & ~(size_t)255;          // 256 ints
  int* col = (int*)(w + off_col);
  float* wgt = (float*)(w + off_wgt);
  int* rowptr = (int*)(w + off_rowptr);
  int* cursor = (int*)(w + off_cursor);
  int* bsum = (int*)(w + off_bsum);
  int* bsumEx = bsum + 256;
  float* neigh = (float*)d_ws;                                // n*128 floats (overlaps CSR)

  const int total = n + 1;
  const int nb = (total + 1023) / 1024;                       // scan blocks (<= 64)

  (void)hipMemsetAsync(rowptr, 0, (size_t)total * sizeof(int), stream);
  deg_kernel<<<(E + 255) / 256, 256, 0, stream>>>(dst, rowptr, E);
  scan1_kernel<<<nb, 256, 0, stream>>>(rowptr, bsum, total);
  scan2_kernel<<<1, 64, 0, stream>>>(bsum, bsumEx, nb);
  scan3_kernel<<<nb, 256, 0, stream>>>(rowptr, cursor, bsumEx, total, n);
  fill_kernel<<<(E + 255) / 256, 256, 0, stream>>>(src, dst, ew, cursor, col, wgt, E);

  // agg -> d_out (fully overwritten every call; poison-safe)
  gather_kernel<<<(n * 64 + 255) / 256, 256, 0, stream>>>(feat, rowptr, col, wgt, out, n);

  const int ngrp = (n + NROWS - 1) / NROWS;
  const int gblocks = ngrp < 512 ? ngrp : 512;
  // neigh = agg @ Wn.T   (reads d_out, writes ws; CSR now dead)
  gemm_h_kernel<<<gblocks, 256, 0, stream>>>(out, Wn, neigh, n);
  // out = feat @ Ws.T + b + neigh
  finalize_kernel<<<gblocks, 256, 0, stream>>>(feat, Ws, bs, neigh, out, n);
}

// Round 4
// 262.913 us; speedup vs baseline: 5.6444x; 1.0661x over previous
//
#include <hip/hip_runtime.h>

#define NROWS 16

__device__ __forceinline__ unsigned f2bf(float x) {
  unsigned u = __float_as_uint(x);
  return (u + 0x7fffu + ((u >> 16) & 1u)) >> 16;   // RN-even
}

// ---------------- feat -> bf16 packed copy ----------------
// fb[i] packs channels {2i, 2i+1} of the flattened feat.
__global__ __launch_bounds__(256) void cvt_kernel(
    const float* __restrict__ feat, unsigned* __restrict__ fb, int total2) {
  for (int i = blockIdx.x * 256 + threadIdx.x; i < total2; i += gridDim.x * 256) {
    float2 v = ((const float2*)feat)[i];
    fb[i] = f2bf(v.x) | (f2bf(v.y) << 16);
  }
}

// ---------------- CSR build ----------------

__global__ __launch_bounds__(256) void deg_kernel(
    const int* __restrict__ dst, int* __restrict__ rowptr, int E) {
  int e = blockIdx.x * 256 + threadIdx.x;
  if (e < E) atomicAdd(&rowptr[dst[e] + 1], 1);
}

__global__ __launch_bounds__(256) void scan1_kernel(
    int* __restrict__ data, int* __restrict__ bsum, int total) {
  __shared__ int tsum[256];
  const int tid = threadIdx.x;
  const int base = blockIdx.x * 1024 + tid * 4;
  int v0 = 0, v1 = 0, v2 = 0, v3 = 0;
  if (base + 3 < total) {
    int4 v = *(const int4*)(data + base);
    v0 = v.x; v1 = v.y; v2 = v.z; v3 = v.w;
  } else {
    if (base + 0 < total) v0 = data[base + 0];
    if (base + 1 < total) v1 = data[base + 1];
    if (base + 2 < total) v2 = data[base + 2];
    if (base + 3 < total) v3 = data[base + 3];
  }
  v1 += v0; v2 += v1; v3 += v2;
  tsum[tid] = v3;
  __syncthreads();
  for (int off = 1; off < 256; off <<= 1) {
    int t = (tid >= off) ? tsum[tid - off] : 0;
    __syncthreads();
    tsum[tid] += t;
    __syncthreads();
  }
  const int excl = (tid > 0) ? tsum[tid - 1] : 0;
  v0 += excl; v1 += excl; v2 += excl; v3 += excl;
  if (base + 3 < total) {
    *(int4*)(data + base) = make_int4(v0, v1, v2, v3);
  } else {
    if (base + 0 < total) data[base + 0] = v0;
    if (base + 1 < total) data[base + 1] = v1;
    if (base + 2 < total) data[base + 2] = v2;
    if (base + 3 < total) data[base + 3] = v3;
  }
  if (tid == 255) bsum[blockIdx.x] = tsum[255];
}

__global__ __launch_bounds__(64) void scan2_kernel(
    const int* __restrict__ bsum, int* __restrict__ bsumEx, int nb) {
  const int lane = threadIdx.x;
  int v = (lane < nb) ? bsum[lane] : 0;
  const int own = v;
  for (int off = 1; off < 64; off <<= 1) {
    int u = __shfl_up(v, off);
    if (lane >= off) v += u;
  }
  if (lane < nb) bsumEx[lane] = v - own;
}

__global__ __launch_bounds__(256) void scan3_kernel(
    int* __restrict__ data, int* __restrict__ cursor,
    const int* __restrict__ bsumEx, int total, int n) {
  const int add = bsumEx[blockIdx.x];
  const int base = blockIdx.x * 1024 + threadIdx.x * 4;
#pragma unroll
  for (int k = 0; k < 4; ++k) {
    int i = base + k;
    if (i < total) {
      int val = data[i] + add;
      data[i] = val;
      if (i < n) cursor[i] = val;
    }
  }
}

__global__ __launch_bounds__(256) void fill_kernel(
    const int* __restrict__ src, const int* __restrict__ dst,
    const float* __restrict__ ew, int* __restrict__ cursor,
    int* __restrict__ col, float* __restrict__ wgt, int E) {
  int e = blockIdx.x * 256 + threadIdx.x;
  if (e >= E) return;
  int d = dst[e];
  int pos = atomicAdd(&cursor[d], 1);
  col[pos] = src[e];
  wgt[pos] = ew[e];
}

// ---------------- gather from bf16 feat ----------------
// One wave per dst node. Lane owns channels {2*lane, 2*lane+1} (one uint).
// col/wgt loaded 64-at-a-time coalesced, broadcast via shfl.
__global__ __launch_bounds__(256) void gather_kernel(
    const unsigned* __restrict__ fb, const int* __restrict__ rowptr,
    const int* __restrict__ col, const float* __restrict__ wgt,
    float* __restrict__ agg, int n) {
  const int wid = (blockIdx.x * 256 + threadIdx.x) >> 6;
  const int lane = threadIdx.x & 63;
  if (wid >= n) return;
  const int s = rowptr[wid];
  const int e = rowptr[wid + 1];
  float acc0 = 0.f, acc1 = 0.f;
  for (int j0 = s; j0 < e; j0 += 64) {
    const int idx = j0 + lane;
    const int cv = (idx < e) ? col[idx] : 0;
    const float wv = (idx < e) ? wgt[idx] : 0.f;
    const int cnt = min(64, e - j0);
    for (int t = 0; t < cnt; ++t) {
      const int c = __shfl(cv, t);
      const float w = __shfl(wv, t);
      const unsigned u = fb[(size_t)c * 64 + lane];
      acc0 += __uint_as_float(u << 16) * w;
      acc1 += __uint_as_float(u & 0xffff0000u) * w;
    }
  }
  const float sc = 1.0f / fmaxf((float)(e - s), 1.0f);
  *(float2*)(agg + (size_t)wid * 128 + lane * 2) = make_float2(acc0 * sc, acc1 * sc);
}

// ---------------- GEMM: out = in @ W.T (float4 LDS inner loop) ----------------
// wT4[k4*128 + c] = W[c][4k4..4k4+3]. Lane reads cols {lane, lane+64} per-lane
// contiguous b128; row fragments are wave-broadcast b128.
__global__ __launch_bounds__(256) void gemm_h_kernel(
    const float* __restrict__ in,
    const float* __restrict__ W,
    float* __restrict__ h, int n) {
  __shared__ float4 wT4[4096];          // 64 KB
  __shared__ float4 fr4[NROWS * 32];    // 8 KB
  const int tid = threadIdx.x;
  for (int i = tid; i < 4096; i += 256) {
    int k4 = i >> 7, c = i & 127;
    wT4[i] = *(const float4*)(W + (size_t)c * 128 + k4 * 4);
  }
  const int lane = tid & 63;
  const int r0 = (tid >> 6) * 4;
  const int ngrp = (n + NROWS - 1) / NROWS;
  for (int rg = blockIdx.x; rg < ngrp; rg += gridDim.x) {
    const int row0 = rg * NROWS;
    __syncthreads();
    if (row0 + NROWS <= n) {
      const float4* fsrc = (const float4*)(in + (size_t)row0 * 128);
      fr4[tid] = fsrc[tid];
      fr4[tid + 256] = fsrc[tid + 256];
    } else {
      float* f = (float*)fr4;
      for (int i = tid; i < NROWS * 128; i += 256) {
        int r = i >> 7;
        f[i] = (row0 + r < n) ? in[(size_t)(row0 + r) * 128 + (i & 127)] : 0.f;
      }
    }
    __syncthreads();
    float a00 = 0, a01 = 0, a10 = 0, a11 = 0, a20 = 0, a21 = 0, a30 = 0, a31 = 0;
#pragma unroll 8
    for (int k4 = 0; k4 < 32; ++k4) {
      const float4 w0 = wT4[(k4 << 7) + lane];
      const float4 w1 = wT4[(k4 << 7) + lane + 64];
      const float4 f0 = fr4[(r0 + 0) * 32 + k4];
      const float4 f1 = fr4[(r0 + 1) * 32 + k4];
      const float4 f2 = fr4[(r0 + 2) * 32 + k4];
      const float4 f3 = fr4[(r0 + 3) * 32 + k4];
      a00 += f0.x * w0.x + f0.y * w0.y + f0.z * w0.z + f0.w * w0.w;
      a01 += f0.x * w1.x + f0.y * w1.y + f0.z * w1.z + f0.w * w1.w;
      a10 += f1.x * w0.x + f1.y * w0.y + f1.z * w0.z + f1.w * w0.w;
      a11 += f1.x * w1.x + f1.y * w1.y + f1.z * w1.z + f1.w * w1.w;
      a20 += f2.x * w0.x + f2.y * w0.y + f2.z * w0.z + f2.w * w0.w;
      a21 += f2.x * w1.x + f2.y * w1.y + f2.z * w1.z + f2.w * w1.w;
      a30 += f3.x * w0.x + f3.y * w0.y + f3.z * w0.z + f3.w * w0.w;
      a31 += f3.x * w1.x + f3.y * w1.y + f3.z * w1.z + f3.w * w1.w;
    }
    const int rr = row0 + r0;
    if (rr + 0 < n) { h[(size_t)(rr + 0) * 128 + lane] = a00; h[(size_t)(rr + 0) * 128 + lane + 64] = a01; }
    if (rr + 1 < n) { h[(size_t)(rr + 1) * 128 + lane] = a10; h[(size_t)(rr + 1) * 128 + lane + 64] = a11; }
    if (rr + 2 < n) { h[(size_t)(rr + 2) * 128 + lane] = a20; h[(size_t)(rr + 2) * 128 + lane + 64] = a21; }
    if (rr + 3 < n) { h[(size_t)(rr + 3) * 128 + lane] = a30; h[(size_t)(rr + 3) * 128 + lane + 64] = a31; }
  }
}

// out = feat @ Ws.T + b + neigh
__global__ __launch_bounds__(256) void finalize_kernel(
    const float* __restrict__ feat,
    const float* __restrict__ W,
    const float* __restrict__ b,
    const float* __restrict__ neigh,
    float* __restrict__ out, int n) {
  __shared__ float4 wT4[4096];
  __shared__ float4 fr4[NROWS * 32];
  const int tid = threadIdx.x;
  for (int i = tid; i < 4096; i += 256) {
    int k4 = i >> 7, c = i & 127;
    wT4[i] = *(const float4*)(W + (size_t)c * 128 + k4 * 4);
  }
  const int lane = tid & 63;
  const int r0 = (tid >> 6) * 4;
  const float b0 = b[lane];
  const float b1 = b[lane + 64];
  const int ngrp = (n + NROWS - 1) / NROWS;
  for (int rg = blockIdx.x; rg < ngrp; rg += gridDim.x) {
    const int row0 = rg * NROWS;
    __syncthreads();
    if (row0 + NROWS <= n) {
      const float4* fsrc = (const float4*)(feat + (size_t)row0 * 128);
      fr4[tid] = fsrc[tid];
      fr4[tid + 256] = fsrc[tid + 256];
    } else {
      float* f = (float*)fr4;
      for (int i = tid; i < NROWS * 128; i += 256) {
        int r = i >> 7;
        f[i] = (row0 + r < n) ? feat[(size_t)(row0 + r) * 128 + (i & 127)] : 0.f;
      }
    }
    __syncthreads();
    float a00 = 0, a01 = 0, a10 = 0, a11 = 0, a20 = 0, a21 = 0, a30 = 0, a31 = 0;
#pragma unroll 8
    for (int k4 = 0; k4 < 32; ++k4) {
      const float4 w0 = wT4[(k4 << 7) + lane];
      const float4 w1 = wT4[(k4 << 7) + lane + 64];
      const float4 f0 = fr4[(r0 + 0) * 32 + k4];
      const float4 f1 = fr4[(r0 + 1) * 32 + k4];
      const float4 f2 = fr4[(r0 + 2) * 32 + k4];
      const float4 f3 = fr4[(r0 + 3) * 32 + k4];
      a00 += f0.x * w0.x + f0.y * w0.y + f0.z * w0.z + f0.w * w0.w;
      a01 += f0.x * w1.x + f0.y * w1.y + f0.z * w1.z + f0.w * w1.w;
      a10 += f1.x * w0.x + f1.y * w0.y + f1.z * w0.z + f1.w * w0.w;
      a11 += f1.x * w1.x + f1.y * w1.y + f1.z * w1.z + f1.w * w1.w;
      a20 += f2.x * w0.x + f2.y * w0.y + f2.z * w0.z + f2.w * w0.w;
      a21 += f2.x * w1.x + f2.y * w1.y + f2.z * w1.z + f2.w * w1.w;
      a30 += f3.x * w0.x + f3.y * w0.y + f3.z * w0.z + f3.w * w0.w;
      a31 += f3.x * w1.x + f3.y * w1.y + f3.z * w1.z + f3.w * w1.w;
    }
    const int rr = row0 + r0;
#pragma unroll
    for (int r = 0; r < 4; ++r) {
      if (rr + r < n) {
        size_t idx = (size_t)(rr + r) * 128 + lane;
        float aa0 = (r == 0) ? a00 : (r == 1) ? a10 : (r == 2) ? a20 : a30;
        float aa1 = (r == 0) ? a01 : (r == 1) ? a11 : (r == 2) ? a21 : a31;
        out[idx] = aa0 + b0 + neigh[idx];
        out[idx + 64] = aa1 + b1 + neigh[idx + 64];
      }
    }
  }
}

extern "C" void kernel_launch(void* const* d_in, const int* in_sizes, int n_in,
                              void* d_out, int out_size, void* d_ws, size_t ws_size,
                              hipStream_t stream) {
  const float* feat = (const float*)d_in[0];
  const int* src = (const int*)d_in[1];
  const int* dst = (const int*)d_in[2];
  const float* ew = (const float*)d_in[3];
  const float* Wn = (const float*)d_in[4];
  const float* Ws = (const float*)d_in[5];
  const float* bs = (const float*)d_in[6];
  const int n = in_sizes[0] / 128;
  const int E = in_sizes[1];
  float* out = (float*)d_out;

  // ws layout (byte offsets). CSR + fb live until gather completes (~19.5MB);
  // neigh (25.6MB) overlaps from 0, written only after gather. peak = 25.6MB.
  char* w = (char*)d_ws;
  size_t off_col = 0;                                               // E ints
  size_t off_wgt = off_col + (size_t)E * 4;                         // E floats
  size_t off_rowptr = off_wgt + (size_t)E * 4;                      // n+1 ints
  size_t off_cursor = (off_rowptr + (size_t)(n + 1) * 4 + 255) & ~(size_t)255;  // n ints
  size_t off_bsum = (off_cursor + (size_t)n * 4 + 255) & ~(size_t)255;          // 512 ints
  size_t off_fb = (off_bsum + 512 * 4 + 255) & ~(size_t)255;        // n*64 uints (bf16x2)
  int* col = (int*)(w + off_col);
  float* wgt = (float*)(w + off_wgt);
  int* rowptr = (int*)(w + off_rowptr);
  int* cursor = (int*)(w + off_cursor);
  int* bsum = (int*)(w + off_bsum);
  int* bsumEx = bsum + 256;
  unsigned* fb = (unsigned*)(w + off_fb);
  float* neigh = (float*)d_ws;                                      // overlaps CSR+fb

  const int total = n + 1;
  const int nb = (total + 1023) / 1024;

  (void)hipMemsetAsync(rowptr, 0, (size_t)total * sizeof(int), stream);
  cvt_kernel<<<1024, 256, 0, stream>>>(feat, fb, n * 64);
  deg_kernel<<<(E + 255) / 256, 256, 0, stream>>>(dst, rowptr, E);
  scan1_kernel<<<nb, 256, 0, stream>>>(rowptr, bsum, total);
  scan2_kernel<<<1, 64, 0, stream>>>(bsum, bsumEx, nb);
  scan3_kernel<<<nb, 256, 0, stream>>>(rowptr, cursor, bsumEx, total, n);
  fill_kernel<<<(E + 255) / 256, 256, 0, stream>>>(src, dst, ew, cursor, col, wgt, E);

  // agg -> d_out
  gather_kernel<<<(n * 64 + 255) / 256, 256, 0, stream>>>(fb, rowptr, col, wgt, out, n);

  const int ngrp = (n + NROWS - 1) / NROWS;
  const int gblocks = ngrp < 512 ? ngrp : 512;
  // neigh = agg @ Wn.T   (reads d_out, writes ws; CSR+fb now dead)
  gemm_h_kernel<<<gblocks, 256, 0, stream>>>(out, Wn, neigh, n);
  // out = feat @ Ws.T + b + neigh
  finalize_kernel<<<gblocks, 256, 0, stream>>>(feat, Ws, bs, neigh, out, n);
}

// Round 5
// 213.627 us; speedup vs baseline: 6.9466x; 1.2307x over previous
//
#include <hip/hip_runtime.h>

typedef __attribute__((ext_vector_type(8))) short bf16x8;
typedef __attribute__((ext_vector_type(4))) float f32x4;

__device__ __forceinline__ unsigned f2bf(float x) {
  unsigned u = __float_as_uint(x);
  return (u + 0x7fffu + ((u >> 16) & 1u)) >> 16;   // RN-even
}

// ---------------- feat -> bf16 packed copy (uint = 2 consecutive bf16) -------
__global__ __launch_bounds__(256) void cvt_kernel(
    const float* __restrict__ feat, unsigned* __restrict__ fb, int total2) {
  for (int i = blockIdx.x * 256 + threadIdx.x; i < total2; i += gridDim.x * 256) {
    float2 v = ((const float2*)feat)[i];
    fb[i] = f2bf(v.x) | (f2bf(v.y) << 16);
  }
}

// ---------------- Ws, Wn -> bf16 ----------------
__global__ __launch_bounds__(256) void wcvt_kernel(
    const float* __restrict__ Ws, const float* __restrict__ Wn,
    unsigned* __restrict__ wsb, unsigned* __restrict__ wnb) {
  int i = blockIdx.x * 256 + threadIdx.x;
  if (i < 8192) {
    float2 a = ((const float2*)Ws)[i];
    wsb[i] = f2bf(a.x) | (f2bf(a.y) << 16);
    float2 b = ((const float2*)Wn)[i];
    wnb[i] = f2bf(b.x) | (f2bf(b.y) << 16);
  }
}

// ---------------- CSR build ----------------

__global__ __launch_bounds__(256) void deg_kernel(
    const int* __restrict__ dst, int* __restrict__ rowptr, int E) {
  int e = blockIdx.x * 256 + threadIdx.x;
  if (e < E) atomicAdd(&rowptr[dst[e] + 1], 1);
}

__global__ __launch_bounds__(256) void scan1_kernel(
    int* __restrict__ data, int* __restrict__ bsum, int total) {
  __shared__ int tsum[256];
  const int tid = threadIdx.x;
  const int base = blockIdx.x * 1024 + tid * 4;
  int v0 = 0, v1 = 0, v2 = 0, v3 = 0;
  if (base + 3 < total) {
    int4 v = *(const int4*)(data + base);
    v0 = v.x; v1 = v.y; v2 = v.z; v3 = v.w;
  } else {
    if (base + 0 < total) v0 = data[base + 0];
    if (base + 1 < total) v1 = data[base + 1];
    if (base + 2 < total) v2 = data[base + 2];
    if (base + 3 < total) v3 = data[base + 3];
  }
  v1 += v0; v2 += v1; v3 += v2;
  tsum[tid] = v3;
  __syncthreads();
  for (int off = 1; off < 256; off <<= 1) {
    int t = (tid >= off) ? tsum[tid - off] : 0;
    __syncthreads();
    tsum[tid] += t;
    __syncthreads();
  }
  const int excl = (tid > 0) ? tsum[tid - 1] : 0;
  v0 += excl; v1 += excl; v2 += excl; v3 += excl;
  if (base + 3 < total) {
    *(int4*)(data + base) = make_int4(v0, v1, v2, v3);
  } else {
    if (base + 0 < total) data[base + 0] = v0;
    if (base + 1 < total) data[base + 1] = v1;
    if (base + 2 < total) data[base + 2] = v2;
    if (base + 3 < total) data[base + 3] = v3;
  }
  if (tid == 255) bsum[blockIdx.x] = tsum[255];
}

__global__ __launch_bounds__(64) void scan2_kernel(
    const int* __restrict__ bsum, int* __restrict__ bsumEx, int nb) {
  const int lane = threadIdx.x;
  int v = (lane < nb) ? bsum[lane] : 0;
  const int own = v;
  for (int off = 1; off < 64; off <<= 1) {
    int u = __shfl_up(v, off);
    if (lane >= off) v += u;
  }
  if (lane < nb) bsumEx[lane] = v - own;
}

__global__ __launch_bounds__(256) void scan3_kernel(
    int* __restrict__ data, int* __restrict__ cursor,
    const int* __restrict__ bsumEx, int total, int n) {
  const int add = bsumEx[blockIdx.x];
  const int base = blockIdx.x * 1024 + threadIdx.x * 4;
#pragma unroll
  for (int k = 0; k < 4; ++k) {
    int i = base + k;
    if (i < total) {
      int val = data[i] + add;
      data[i] = val;
      if (i < n) cursor[i] = val;
    }
  }
}

// One 4B scattered store per edge: (col << 16) | round(w * 65535)
__global__ __launch_bounds__(256) void fill_kernel(
    const int* __restrict__ src, const int* __restrict__ dst,
    const float* __restrict__ ew, int* __restrict__ cursor,
    unsigned* __restrict__ colw, int E) {
  int e = blockIdx.x * 256 + threadIdx.x;
  if (e >= E) return;
  int d = dst[e];
  int pos = atomicAdd(&cursor[d], 1);
  unsigned q = (unsigned)(ew[e] * 65535.0f + 0.5f);
  colw[pos] = ((unsigned)src[e] << 16) | q;
}

// ---------------- gather: agg[d] = mean_e feat_bf16[src_e]*w_e  (f32 out) ----
// One wave per dst node. Lane owns channels {2*lane, 2*lane+1}.
__global__ __launch_bounds__(256) void gather_kernel(
    const unsigned* __restrict__ fb, const int* __restrict__ rowptr,
    const unsigned* __restrict__ colw, float* __restrict__ agg, int n) {
  const int wid = (blockIdx.x * 256 + threadIdx.x) >> 6;
  const int lane = threadIdx.x & 63;
  if (wid >= n) return;
  const int s = rowptr[wid];
  const int e = rowptr[wid + 1];
  float acc0 = 0.f, acc1 = 0.f;
  for (int j0 = s; j0 < e; j0 += 64) {
    const int idx = j0 + lane;
    const unsigned pv = (idx < e) ? colw[idx] : 0u;
    const int cnt = min(64, e - j0);
    for (int t = 0; t < cnt; ++t) {
      const unsigned p = __shfl(pv, t);
      const int c = (int)(p >> 16);
      const float w = (float)(p & 0xffffu) * (1.0f / 65535.0f);
      const unsigned u = fb[(size_t)c * 64 + lane];
      acc0 += __uint_as_float(u << 16) * w;
      acc1 += __uint_as_float(u & 0xffff0000u) * w;
    }
  }
  const float sc = 1.0f / fmaxf((float)(e - s), 1.0f);
  *(float2*)(agg + (size_t)wid * 128 + lane * 2) = make_float2(acc0 * sc, acc1 * sc);
}

// ---------------- fused MFMA GEMM (in-place on d_out) ----------------
// out[r] = feat_bf[r] @ Ws_bf.T + b + aggf32_bf[r] @ Wn_bf.T
// One wave per 16-row strip; wave reads its own agg rows (d_out) then
// overwrites them — strips are row-disjoint, so in-place is race-free.
__global__ __launch_bounds__(256) void fused_gemm_kernel(
    const ushort* __restrict__ fb,   // feat bf16 [n][128]
    const ushort* __restrict__ wsb,  // Ws bf16 [128][128]
    const ushort* __restrict__ wnb,  // Wn bf16 [128][128]
    const float* __restrict__ bsv,   // bias [128]
    float* __restrict__ out,         // in: agg f32; out: final
    int n) {
  const int lane = threadIdx.x & 63;
  const int wid = (blockIdx.x * 256 + threadIdx.x) >> 6;
  const int row0 = wid * 16;
  if (row0 >= n) return;
  const int rlo = lane & 15;
  const int g = lane >> 4;

  f32x4 acc[8];
#pragma unroll
  for (int ct = 0; ct < 8; ++ct) {
    float bv = bsv[ct * 16 + rlo];
    acc[ct] = (f32x4){bv, bv, bv, bv};
  }

  const int rowA = min(row0 + rlo, n - 1);   // clamp stays inside last strip

#pragma unroll
  for (int kc = 0; kc < 4; ++kc) {
    const int k0 = kc * 32 + g * 8;
    const bf16x8 aself = *(const bf16x8*)(fb + (size_t)rowA * 128 + k0);
    const float4 u0 = *(const float4*)(out + (size_t)rowA * 128 + k0);
    const float4 u1 = *(const float4*)(out + (size_t)rowA * 128 + k0 + 4);
    bf16x8 aagg;
    aagg[0] = (short)f2bf(u0.x); aagg[1] = (short)f2bf(u0.y);
    aagg[2] = (short)f2bf(u0.z); aagg[3] = (short)f2bf(u0.w);
    aagg[4] = (short)f2bf(u1.x); aagg[5] = (short)f2bf(u1.y);
    aagg[6] = (short)f2bf(u1.z); aagg[7] = (short)f2bf(u1.w);
#pragma unroll
    for (int ct = 0; ct < 8; ++ct) {
      const int c = ct * 16 + rlo;
      const bf16x8 bs = *(const bf16x8*)(wsb + (size_t)c * 128 + k0);
      const bf16x8 bn = *(const bf16x8*)(wnb + (size_t)c * 128 + k0);
      acc[ct] = __builtin_amdgcn_mfma_f32_16x16x32_bf16(aself, bs, acc[ct], 0, 0, 0);
      acc[ct] = __builtin_amdgcn_mfma_f32_16x16x32_bf16(aagg, bn, acc[ct], 0, 0, 0);
    }
  }

  // C/D layout: col = lane&15 (+ct*16), row = (lane>>4)*4 + j   [m89-verified]
#pragma unroll
  for (int ct = 0; ct < 8; ++ct) {
#pragma unroll
    for (int j = 0; j < 4; ++j) {
      const int r = row0 + g * 4 + j;
      if (r < n) out[(size_t)r * 128 + ct * 16 + rlo] = acc[ct][j];
    }
  }
}

extern "C" void kernel_launch(void* const* d_in, const int* in_sizes, int n_in,
                              void* d_out, int out_size, void* d_ws, size_t ws_size,
                              hipStream_t stream) {
  const float* feat = (const float*)d_in[0];
  const int* src = (const int*)d_in[1];
  const int* dst = (const int*)d_in[2];
  const float* ew = (const float*)d_in[3];
  const float* Wn = (const float*)d_in[4];
  const float* Ws = (const float*)d_in[5];
  const float* bs = (const float*)d_in[6];
  const int n = in_sizes[0] / 128;
  const int E = in_sizes[1];
  float* out = (float*)d_out;

  // ws layout: colw 3.2MB + rowptr/cursor/bsum ~0.5MB + fb 12.8MB + W 64KB
  // total ~16.6MB (< 19.8MB proven in r4).
  char* w = (char*)d_ws;
  size_t off_colw = 0;                                              // E uints
  size_t off_rowptr = (off_colw + (size_t)E * 4 + 255) & ~(size_t)255;           // n+1 ints
  size_t off_cursor = (off_rowptr + (size_t)(n + 1) * 4 + 255) & ~(size_t)255;   // n ints
  size_t off_bsum = (off_cursor + (size_t)n * 4 + 255) & ~(size_t)255;           // 512 ints
  size_t off_fb = (off_bsum + 512 * 4 + 255) & ~(size_t)255;        // n*64 uints
  size_t off_wsb = (off_fb + (size_t)n * 64 * 4 + 255) & ~(size_t)255;  // 8192 uints
  size_t off_wnb = off_wsb + 8192 * 4;                              // 8192 uints
  unsigned* colw = (unsigned*)(w + off_colw);
  int* rowptr = (int*)(w + off_rowptr);
  int* cursor = (int*)(w + off_cursor);
  int* bsum = (int*)(w + off_bsum);
  int* bsumEx = bsum + 256;
  unsigned* fb = (unsigned*)(w + off_fb);
  unsigned* wsb = (unsigned*)(w + off_wsb);
  unsigned* wnb = (unsigned*)(w + off_wnb);

  const int total = n + 1;
  const int nb = (total + 1023) / 1024;

  (void)hipMemsetAsync(rowptr, 0, (size_t)total * sizeof(int), stream);
  cvt_kernel<<<1024, 256, 0, stream>>>(feat, fb, n * 64);
  wcvt_kernel<<<32, 256, 0, stream>>>(Ws, Wn, wsb, wnb);
  deg_kernel<<<(E + 255) / 256, 256, 0, stream>>>(dst, rowptr, E);
  scan1_kernel<<<nb, 256, 0, stream>>>(rowptr, bsum, total);
  scan2_kernel<<<1, 64, 0, stream>>>(bsum, bsumEx, nb);
  scan3_kernel<<<nb, 256, 0, stream>>>(rowptr, cursor, bsumEx, total, n);
  fill_kernel<<<(E + 255) / 256, 256, 0, stream>>>(src, dst, ew, cursor, colw, E);

  // agg (f32) -> d_out
  gather_kernel<<<(n * 64 + 255) / 256, 256, 0, stream>>>(fb, rowptr, colw, out, n);

  // fused: out = feat@Ws.T + b + agg@Wn.T   (in-place on d_out)
  const int nstrips = (n + 15) / 16;
  fused_gemm_kernel<<<(nstrips + 3) / 4, 256, 0, stream>>>(
      (const ushort*)fb, (const ushort*)wsb, (const ushort*)wnb, bs, out, n);
}